// Round 12
// baseline (604.673 us; speedup 1.0000x reference)
//
#include <hip/hip_runtime.h>
#include <stdint.h>

#define NA 200000
#define NB 200000
#define NG 10000

typedef short bf16x8 __attribute__((ext_vector_type(8)));
typedef float f32x4 __attribute__((ext_vector_type(4)));

__device__ __forceinline__ float bf2f(unsigned short u){
  union { unsigned int i; float f; } v; v.i = ((unsigned int)u) << 16; return v.f;
}
__device__ __forceinline__ unsigned short f2bf(float f){
  union { float f; unsigned int i; } v; v.f = f;
  unsigned int x = v.i;
  unsigned int r = (x + 0x7FFFu + ((x >> 16) & 1u)) >> 16;
  if ((x & 0x7F800000u) == 0x7F800000u) r = x >> 16;
  return (unsigned short)r;
}
// HW packed f32->2xbf16 (RNE), 1 instruction
__device__ __forceinline__ unsigned int cvtpk(float lo, float hi){
  unsigned int r;
  asm("v_cvt_pk_bf16_f32 %0, %1, %2" : "=v"(r) : "v"(lo), "v"(hi));
  return r;
}
// fire-and-forget packed bf16 atomic add (2 cols per dword)
__device__ __forceinline__ void atomic_pk_add(unsigned int* addr, unsigned int pk){
  asm volatile("global_atomic_pk_add_bf16 %0, %1, off" :: "v"(addr), "v"(pk) : "memory");
}
// unpack pk pair, scale by inv, repack
__device__ __forceinline__ unsigned int scale_pk(unsigned int pk, float inv){
  union { unsigned int u; float f; } lo, hi;
  lo.u = pk << 16; hi.u = pk & 0xffff0000u;
  return cvtpk(lo.f * inv, hi.f * inv);
}
__device__ __forceinline__ float softplus_f(float x){
  float t = __builtin_exp2f(-fabsf(x) * 1.44269504089f);
  return fmaxf(x, 0.0f) + 0.69314718056f * __builtin_log2f(1.0f + t);
}
__device__ __forceinline__ float ldv(const void* p, size_t off, int isbf){
  return isbf ? bf2f(((const unsigned short*)p)[off]) : ((const float*)p)[off];
}
__device__ __forceinline__ int clampi(int v, int hi){
  return v < 0 ? 0 : (v > hi ? hi : v);
}
__device__ __forceinline__ uint4 load8bf(const void* p, size_t off, int isbf){
  if (isbf) return *(const uint4*)((const unsigned short*)p + off);
  const float4* f4 = (const float4*)((const float*)p + off);
  float4 a = f4[0], b = f4[1];
  uint4 r;
  r.x = cvtpk(a.x, a.y); r.y = cvtpk(a.z, a.w);
  r.z = cvtpk(b.x, b.y); r.w = cvtpk(b.z, b.w);
  return r;
}
// load 4 pk dwords (8 bf16) and scale by 1/cnt
__device__ __forceinline__ uint4 mean8pk(const void* s, size_t dw, float cv){
  float inv = cv > 0.f ? 1.f / cv : 0.f;
  uint4 p = *(const uint4*)((const unsigned int*)s + dw);
  uint4 r;
  r.x = scale_pk(p.x, inv); r.y = scale_pk(p.y, inv);
  r.z = scale_pk(p.z, inv); r.w = scale_pk(p.w, inv);
  return r;
}

// ---- probes: fl[0]=feats-bf16, fl[1]=weights-bf16, fl[2]=indices-int64 ----
__global__ __launch_bounds__(64) void probe_all(
    const unsigned short* __restrict__ af, const unsigned short* __restrict__ w,
    const int* __restrict__ amol, int* __restrict__ fl)
{
  int l = threadIdx.x;
  unsigned short ua = af[2 * l], uw = w[2 * l];
  int ea = (ua >> 7) & 0xFF, ew = (uw >> 7) & 0xFF;
  unsigned long long ma = __ballot(ea >= 0x70 && ea <= 0x8F);
  unsigned long long mw = __ballot(ew >= 0x70 && ew <= 0x8F);
  unsigned long long mi = __ballot(amol[2 * l + 1] == 0);
  if (l == 0) {
    fl[0] = (__popcll(ma) >= 32) ? 1 : 0;
    fl[1] = (__popcll(mw) >= 32) ? 1 : 0;
    fl[2] = (__popcll(mi) == 64) ? 1 : 0;
  }
}

__global__ void sentinel(float* outf, float code){ outf[0] = code; }

// ---- bond->atom edge sum: packed bf16 atomics (2 cols per dword) ----
__global__ __launch_bounds__(256) void edge_sum_pk(
    const void* __restrict__ bond, const int* __restrict__ ba,
    unsigned int* __restrict__ sums, float* __restrict__ cnt,
    const int* __restrict__ fl)
{
  const int featbf = fl[0];
  const int istr = 1 + fl[2];
  int cp = threadIdx.x & 63;     // column pair
  int rl = threadIdx.x >> 6;     // 4 rows per block
  for (long b = (long)blockIdx.x * 4 + rl; b < NB; b += (long)gridDim.x * 4) {
    unsigned int pk;
    if (featbf) pk = ((const unsigned int*)bond)[(size_t)b * 64 + cp];
    else {
      float2 f = ((const float2*)bond)[(size_t)b * 64 + cp];
      pk = cvtpk(f.x, f.y);
    }
    int d0 = ba[(size_t)(2 * b)     * istr];
    int d1 = ba[(size_t)(2 * b + 1) * istr];
    if (d0 >= 0 && d0 < NA) atomic_pk_add(sums + (size_t)d0 * 64 + cp, pk);
    if (d1 >= 0 && d1 < NA) atomic_pk_add(sums + (size_t)d1 * 64 + cp, pk);
    if (cp == 0) {
      if (d0 >= 0 && d0 < NA) atomicAdd(cnt + d0, 1.0f);
      if (d1 >= 0 && d1 < NA) atomicAdd(cnt + d1, 1.0f);
    }
  }
}

// ---- repack weights [K][128] -> MFMA B-fragment-major bf16 ----
__global__ __launch_bounds__(64) void repack_w(
    const void* __restrict__ w, unsigned short* __restrict__ dst,
    const int* __restrict__ fl)
{
  int wbf = fl[1];
  int f = blockIdx.x; int kt = f >> 3; int nb = f & 7; int l = threadIdx.x;
  alignas(16) unsigned short t[8];
  #pragma unroll
  for (int i = 0; i < 8; i++) {
    size_t off = (size_t)(kt * 32 + ((l >> 4) << 3) + i) * 128 + nb * 16 + (l & 15);
    t[i] = f2bf(ldv(w, off, wbf));
  }
  *(uint4*)(dst + (size_t)f * 512 + l * 8) = *(const uint4*)t;
}

// ---- one layer on a 16-row tile; wave handles col-blocks {2w, 2w+1} ----
// FINAL: f32 stores + column-pair packed-bf16 atomics to gs (even lanes)
template<int KT, bool FINAL>
__device__ __forceinline__ void run_layer16(
    const char* inbuf, int rowbIn,
    const unsigned short* __restrict__ wpL, const void* __restrict__ biasL, int wbf,
    char* outbuf,
    float* __restrict__ outSec, unsigned short* __restrict__ outBf,
    unsigned int* __restrict__ gs, float* __restrict__ gc,
    const int* __restrict__ idxS, int istr, int row0, int rowHi,
    int lane, int wave)
{
  const int nb0 = wave * 2;
  const int colA = lane & 15;
  const int swz = (lane & 7) << 4;
  const int kb = (lane >> 4) << 4;
  float bb0 = ldv(biasL, nb0 * 16 + colA, wbf);
  float bb1 = ldv(biasL, nb0 * 16 + 16 + colA, wbf);
  f32x4 acc0 = {bb0, bb0, bb0, bb0};
  f32x4 acc1 = {bb1, bb1, bb1, bb1};
  #pragma unroll
  for (int kt = 0; kt < KT; ++kt) {
    bf16x8 b0 = *(const bf16x8*)(wpL + ((size_t)(kt * 8 + nb0) << 9) + lane * 8);
    bf16x8 b1 = *(const bf16x8*)(wpL + ((size_t)(kt * 8 + nb0 + 1) << 9) + lane * 8);
    bf16x8 a = *(const bf16x8*)(inbuf + colA * rowbIn + ((kt * 64 + kb) ^ swz));
    acc0 = __builtin_amdgcn_mfma_f32_16x16x32_bf16(a, b0, acc0, 0, 0, 0);
    acc1 = __builtin_amdgcn_mfma_f32_16x16x32_bf16(a, b1, acc1, 0, 0, 0);
  }
  #pragma unroll
  for (int j = 0; j < 2; j++) {
    f32x4 acc = j ? acc1 : acc0;
    int col = (nb0 + j) * 16 + colA;
    #pragma unroll
    for (int rp = 0; rp < 2; rp++) {
      int r0 = ((lane >> 4) << 2) + 2 * rp;
      float v0 = acc[2 * rp], v1 = acc[2 * rp + 1];
      if (!FINAL) {
        float s0 = softplus_f(v0), s1v = softplus_f(v1);
        unsigned int pk = cvtpk(s0, s1v);
        *(unsigned short*)(outbuf + r0 * 256 + ((col * 2) ^ ((r0 & 7) << 4)))
            = (unsigned short)(pk & 0xffffu);
        *(unsigned short*)(outbuf + (r0 + 1) * 256 + ((col * 2) ^ (((r0 + 1) & 7) << 4)))
            = (unsigned short)(pk >> 16);
      } else {
        int g0 = row0 + r0, g1 = g0 + 1;
        if (g0 < rowHi) outSec[(size_t)g0 * 128 + col] = v0;
        if (g1 < rowHi) outSec[(size_t)g1 * 128 + col] = v1;
        if (outBf) {
          unsigned int pk = cvtpk(v0, v1);
          if (g0 < rowHi) outBf[(size_t)g0 * 128 + col] = (unsigned short)(pk & 0xffffu);
          if (g1 < rowHi) outBf[(size_t)g1 * 128 + col] = (unsigned short)(pk >> 16);
        }
        if (gs) {
          // pair adjacent columns of the SAME row via lane^1 exchange
          float p0 = __shfl_xor(v0, 1);
          float p1 = __shfl_xor(v1, 1);
          if ((lane & 1) == 0) {
            if (g0 < rowHi) {
              int g = idxS[(size_t)g0 * istr];
              if (g >= 0 && g < NG)
                atomic_pk_add(gs + (size_t)g * 64 + (col >> 1), cvtpk(v0, p0));
            }
            if (g1 < rowHi) {
              int g = idxS[(size_t)g1 * istr];
              if (g >= 0 && g < NG)
                atomic_pk_add(gs + (size_t)g * 64 + (col >> 1), cvtpk(v1, p1));
            }
          }
          if (wave == 0 && colA == 0 && j == 0) {
            if (g0 < rowHi) { int g = idxS[(size_t)g0 * istr];
              if (g >= 0 && g < NG) atomicAdd(gc + g, 1.0f); }
            if (g1 < rowHi) { int g = idxS[(size_t)g1 * istr];
              if (g >= 0 && g < NG) atomicAdd(gc + g, 1.0f); }
          }
        }
      }
    }
  }
}

// ---- fused 3-layer MFMA MLP over 16-row tiles ----
// MODE 0: atom  cat=[atom | mean(pk s1,c1) | glob[amol]]   KIN=384
// MODE 1: bond  cat=[bond | A[ba0] | A[ba1] | glob]        KIN=512
// MODE 2: glob  cat=[glob | mean(pk s1,c1) | mean(pk s2,c2)] KIN=384
template<int KIN, int MODE>
__global__ __launch_bounds__(256, 8) void mfma_mlp(
    const void* __restrict__ x0,
    const void* __restrict__ s1, const float* __restrict__ c1,
    const void* __restrict__ s2, const float* __restrict__ c2,
    const void* __restrict__ gfv,
    const int* __restrict__ idxA, const int* __restrict__ idxS,
    const float* __restrict__ gatherA, const unsigned short* __restrict__ gatherBf,
    const unsigned short* __restrict__ wp0, const unsigned short* __restrict__ wp1,
    const unsigned short* __restrict__ wp2,
    const void* __restrict__ b0, const void* __restrict__ b1,
    const void* __restrict__ b2,
    float* __restrict__ outSec, unsigned short* __restrict__ outBf,
    unsigned int* __restrict__ gs, float* __restrict__ gc,
    int rowHi, const int* __restrict__ fl)
{
  constexpr int ROWB = KIN * 2;
  constexpr int CATB = 16 * ROWB;
  constexpr int CPR  = KIN / 8;
  __shared__ char sm[CATB + 4096];
  char* act0 = sm + CATB;
  char* act1 = sm;          // aliases cat (dead after layer 0)
  const int tid = threadIdx.x;
  const int row0 = blockIdx.x * 16;
  const int featbf = fl[0], wbf = fl[1], istr = 1 + fl[2];

  // ---- stage concatenated input tile as swizzled bf16 ----
  for (int ch = tid; ch < 16 * CPR; ch += 256) {
    int r = ch / CPR, c8 = ch % CPR;
    int row = row0 + r;
    int seg = c8 * 8;
    uint4 h4;
    if (row >= rowHi) {
      h4 = uint4{0, 0, 0, 0};
    } else if constexpr (MODE == 0) {
      if (seg < 128)       h4 = load8bf(x0, (size_t)row * 128 + seg, featbf);
      else if (seg < 256)  h4 = mean8pk(s1, (size_t)row * 64 + ((seg - 128) >> 1), c1[row]);
      else { int g = clampi(idxA[(size_t)row * istr], NG - 1);
             h4 = load8bf(gfv, (size_t)g * 128 + seg - 256, featbf); }
    } else if constexpr (MODE == 1) {
      if (seg < 128)       h4 = load8bf(x0, (size_t)row * 128 + seg, featbf);
      else if (seg < 384) {
        int q = (seg < 256) ? 0 : 1;
        int a = clampi(idxA[(size_t)(row * 2 + q) * istr], NA - 1);
        int sc = seg - 128 - q * 128;
        if (gatherBf) h4 = *(const uint4*)(gatherBf + (size_t)a * 128 + sc);
        else          h4 = load8bf(gatherA, (size_t)a * 128 + sc, 0);
      } else { int g = clampi(idxS[(size_t)row * istr], NG - 1);
             h4 = load8bf(gfv, (size_t)g * 128 + seg - 384, featbf); }
    } else {
      if (seg < 128)       h4 = load8bf(x0, (size_t)row * 128 + seg, featbf);
      else if (seg < 256)  h4 = mean8pk(s1, (size_t)row * 64 + ((seg - 128) >> 1), c1[row]);
      else                 h4 = mean8pk(s2, (size_t)row * 64 + ((seg - 256) >> 1), c2[row]);
    }
    *(uint4*)(sm + r * ROWB + ((c8 * 16) ^ ((r & 7) << 4))) = h4;
  }
  __syncthreads();

  const int lane = tid & 63, wave = tid >> 6;
  run_layer16<KIN / 32, false>(sm, ROWB, wp0, b0, wbf, act0,
                               nullptr, nullptr, nullptr, nullptr, nullptr, 1, 0, 0, lane, wave);
  __syncthreads();
  run_layer16<4, false>(act0, 256, wp1, b1, wbf, act1,
                        nullptr, nullptr, nullptr, nullptr, nullptr, 1, 0, 0, lane, wave);
  __syncthreads();
  run_layer16<4, true>(act1, 256, wp2, b2, wbf, nullptr,
                       outSec, outBf, gs, gc, idxS, istr, row0, rowHi, lane, wave);
}

extern "C" void kernel_launch(void* const* d_in, const int* in_sizes, int n_in,
                              void* d_out, int out_size, void* d_ws, size_t ws_size,
                              hipStream_t stream)
{
  const void* atomF = d_in[0];
  const void* bondF = d_in[1];
  const void* globF = d_in[2];
  const int* bondAtom = (const int*)d_in[3];
  const int* atomMol  = (const int*)d_in[4];
  const int* bondMol  = (const int*)d_in[5];
  const void* W[18];
  for (int i = 0; i < 18; i++) W[i] = d_in[6 + i];

  float* outAtom = (float*)d_out;              // f32 (proven R6/R7)
  float* outBond = outAtom + (size_t)NA * 128;
  float* outGlob = outBond + (size_t)NB * 128;

  // d_out-borrowed scratch: pk edge sums in outBond, cnt in outGlob
  unsigned int* sums = (unsigned int*)outBond;
  float* cnt = outGlob;

  // ---- contract validation ----
  const int expect[24] = {
    NA*128, NB*128, NG*128, NB*2, NA, NB,
    384*128, 128, 128*128, 128, 128*128, 128,
    512*128, 128, 128*128, 128, 128*128, 128,
    384*128, 128, 128*128, 128, 128*128, 128 };
  if (n_in != 24) { sentinel<<<1,1,0,stream>>>(outAtom, 8192.0f); return; }
  for (int i = 0; i < 24; i++)
    if (in_sizes[i] != expect[i]) {
      sentinel<<<1,1,0,stream>>>(outAtom, 16384.0f + 256.0f * (float)i);
      return;
    }
  if (out_size != (NA + NB + NG) * 128) {
    sentinel<<<1,1,0,stream>>>(outAtom, 1024.0f); return;
  }

  // ---- ws layout: fl | wp 512KB | gs pk 5.2MB | [opt] atomBf 51.2MB ----
  char* ws = (char*)d_ws;
  int* fl = (int*)ws;                                   // 256 B
  unsigned short* wp = (unsigned short*)(ws + 256);     // 512 KiB
  const size_t gsOff = 256 + 524288;
  unsigned int* gsA = (unsigned int*)(ws + gsOff);      // NG*64 dwords = 2.56MB
  float* gcA = (float*)(ws + gsOff + 2560000);          // 40KB
  unsigned int* gsB = (unsigned int*)(ws + gsOff + 2600000);
  float* gcB = (float*)(ws + gsOff + 5160000);
  const size_t bfOff = gsOff + 5200000;
  unsigned short* atomBf =
      (ws_size >= bfOff + (size_t)NA * 256 + 4096) ? (unsigned short*)(ws + bfOff) : nullptr;

  probe_all<<<1, 64, 0, stream>>>((const unsigned short*)atomF,
                                  (const unsigned short*)W[0], atomMol, fl);
  hipMemsetAsync(ws + gsOff, 0, 5200000, stream);
  hipMemsetAsync(outBond, 0, (size_t)NA * 256, stream);   // pk edge sums
  hipMemsetAsync(outGlob, 0, (size_t)NA * 4, stream);     // cnt

  // ---- weight repack (fragment-major bf16); offsets in ushorts ----
  repack_w<<<96, 64, 0, stream>>>(W[0],  wp + 0,      fl);
  repack_w<<<32, 64, 0, stream>>>(W[2],  wp + 49152,  fl);
  repack_w<<<32, 64, 0, stream>>>(W[4],  wp + 65536,  fl);
  repack_w<<<128,64, 0, stream>>>(W[6],  wp + 81920,  fl);
  repack_w<<<32, 64, 0, stream>>>(W[8],  wp + 147456, fl);
  repack_w<<<32, 64, 0, stream>>>(W[10], wp + 163840, fl);
  repack_w<<<96, 64, 0, stream>>>(W[12], wp + 180224, fl);
  repack_w<<<32, 64, 0, stream>>>(W[14], wp + 229376, fl);
  repack_w<<<32, 64, 0, stream>>>(W[16], wp + 245760, fl);

  // ---- stage 0: edge-mean accumulation (packed bf16 atomics) ----
  edge_sum_pk<<<2048, 256, 0, stream>>>(bondF, bondAtom, sums, cnt, fl);

  // ---- stage 1: atoms ----
  mfma_mlp<384, 0><<<(NA + 15) / 16, 256, 0, stream>>>(
      atomF, sums, cnt, nullptr, nullptr, globF, atomMol, atomMol, nullptr, nullptr,
      wp + 0, wp + 49152, wp + 65536, W[1], W[3], W[5],
      outAtom, atomBf, gsA, gcA, NA, fl);

  // ---- stage 2: bonds ----
  mfma_mlp<512, 1><<<(NB + 15) / 16, 256, 0, stream>>>(
      bondF, nullptr, nullptr, nullptr, nullptr, globF, bondAtom, bondMol,
      outAtom, atomBf,
      wp + 81920, wp + 147456, wp + 163840, W[7], W[9], W[11],
      outBond, nullptr, gsB, gcB, NB, fl);

  // ---- stage 3: globals ----
  mfma_mlp<384, 2><<<(NG + 15) / 16, 256, 0, stream>>>(
      globF, gsA, gcA, gsB, gcB, nullptr, nullptr, nullptr, nullptr, nullptr,
      wp + 180224, wp + 229376, wp + 245760, W[13], W[15], W[17],
      outGlob, nullptr, nullptr, nullptr, NG, fl);
}

// Round 13
// 549.914 us; speedup vs baseline: 1.0996x; 1.0996x over previous
//
#include <hip/hip_runtime.h>
#include <stdint.h>

#define NA 200000
#define NB 200000
#define NG 10000

typedef short bf16x8 __attribute__((ext_vector_type(8)));
typedef float f32x4 __attribute__((ext_vector_type(4)));

__device__ __forceinline__ float bf2f(unsigned short u){
  union { unsigned int i; float f; } v; v.i = ((unsigned int)u) << 16; return v.f;
}
__device__ __forceinline__ unsigned short f2bf(float f){
  union { float f; unsigned int i; } v; v.f = f;
  unsigned int x = v.i;
  unsigned int r = (x + 0x7FFFu + ((x >> 16) & 1u)) >> 16;
  if ((x & 0x7F800000u) == 0x7F800000u) r = x >> 16;
  return (unsigned short)r;
}
// HW packed f32->2xbf16 (RNE), 1 instruction
__device__ __forceinline__ unsigned int cvtpk(float lo, float hi){
  unsigned int r;
  asm("v_cvt_pk_bf16_f32 %0, %1, %2" : "=v"(r) : "v"(lo), "v"(hi));
  return r;
}
// fire-and-forget packed bf16 atomic add (2 cols per dword)
__device__ __forceinline__ void atomic_pk_add(unsigned int* addr, unsigned int pk){
  asm volatile("global_atomic_pk_add_bf16 %0, %1, off" :: "v"(addr), "v"(pk) : "memory");
}
// unpack pk pair, scale by inv, repack
__device__ __forceinline__ unsigned int scale_pk(unsigned int pk, float inv){
  union { unsigned int u; float f; } lo, hi;
  lo.u = pk << 16; hi.u = pk & 0xffff0000u;
  return cvtpk(lo.f * inv, hi.f * inv);
}
__device__ __forceinline__ float softplus_f(float x){
  float t = __builtin_exp2f(-fabsf(x) * 1.44269504089f);
  return fmaxf(x, 0.0f) + 0.69314718056f * __builtin_log2f(1.0f + t);
}
__device__ __forceinline__ float ldv(const void* p, size_t off, int isbf){
  return isbf ? bf2f(((const unsigned short*)p)[off]) : ((const float*)p)[off];
}
__device__ __forceinline__ int clampi(int v, int hi){
  return v < 0 ? 0 : (v > hi ? hi : v);
}
__device__ __forceinline__ uint4 load8bf(const void* p, size_t off, int isbf){
  if (isbf) return *(const uint4*)((const unsigned short*)p + off);
  const float4* f4 = (const float4*)((const float*)p + off);
  float4 a = f4[0], b = f4[1];
  uint4 r;
  r.x = cvtpk(a.x, a.y); r.y = cvtpk(a.z, a.w);
  r.z = cvtpk(b.x, b.y); r.w = cvtpk(b.z, b.w);
  return r;
}
// 8 f32 -> 8 bf16 scaled by 1/cnt
__device__ __forceinline__ uint4 mean8(const float* sp, float cv){
  float inv = cv > 0.f ? 1.f / cv : 0.f;
  const float4* s4 = (const float4*)sp;
  float4 a = s4[0], b = s4[1];
  uint4 r;
  r.x = cvtpk(a.x * inv, a.y * inv); r.y = cvtpk(a.z * inv, a.w * inv);
  r.z = cvtpk(b.x * inv, b.y * inv); r.w = cvtpk(b.z * inv, b.w * inv);
  return r;
}
// 4 pk dwords (8 bf16) scaled by 1/cnt
__device__ __forceinline__ uint4 mean8pk(const void* s, size_t dw, float cv){
  float inv = cv > 0.f ? 1.f / cv : 0.f;
  uint4 p = *(const uint4*)((const unsigned int*)s + dw);
  uint4 r;
  r.x = scale_pk(p.x, inv); r.y = scale_pk(p.y, inv);
  r.z = scale_pk(p.z, inv); r.w = scale_pk(p.w, inv);
  return r;
}

// ---- probes: fl[0]=feats-bf16, fl[1]=weights-bf16, fl[2]=indices-int64 ----
__global__ __launch_bounds__(64) void probe_all(
    const unsigned short* __restrict__ af, const unsigned short* __restrict__ w,
    const int* __restrict__ amol, int* __restrict__ fl)
{
  int l = threadIdx.x;
  unsigned short ua = af[2 * l], uw = w[2 * l];
  int ea = (ua >> 7) & 0xFF, ew = (uw >> 7) & 0xFF;
  unsigned long long ma = __ballot(ea >= 0x70 && ea <= 0x8F);
  unsigned long long mw = __ballot(ew >= 0x70 && ew <= 0x8F);
  unsigned long long mi = __ballot(amol[2 * l + 1] == 0);
  if (l == 0) {
    fl[0] = (__popcll(ma) >= 32) ? 1 : 0;
    fl[1] = (__popcll(mw) >= 32) ? 1 : 0;
    fl[2] = (__popcll(mi) == 64) ? 1 : 0;
  }
}

__global__ void sentinel(float* outf, float code){ outf[0] = code; }

// ---- bond->atom edge sum: packed bf16 atomics (2 cols per dword) ----
__global__ __launch_bounds__(256) void edge_sum_pk(
    const void* __restrict__ bond, const int* __restrict__ ba,
    unsigned int* __restrict__ sums, float* __restrict__ cnt,
    const int* __restrict__ fl)
{
  const int featbf = fl[0];
  const int istr = 1 + fl[2];
  int cp = threadIdx.x & 63;
  int rl = threadIdx.x >> 6;
  for (long b = (long)blockIdx.x * 4 + rl; b < NB; b += (long)gridDim.x * 4) {
    unsigned int pk;
    if (featbf) pk = ((const unsigned int*)bond)[(size_t)b * 64 + cp];
    else {
      float2 f = ((const float2*)bond)[(size_t)b * 64 + cp];
      pk = cvtpk(f.x, f.y);
    }
    int d0 = ba[(size_t)(2 * b)     * istr];
    int d1 = ba[(size_t)(2 * b + 1) * istr];
    if (d0 >= 0 && d0 < NA) atomic_pk_add(sums + (size_t)d0 * 64 + cp, pk);
    if (d1 >= 0 && d1 < NA) atomic_pk_add(sums + (size_t)d1 * 64 + cp, pk);
    if (cp == 0) {
      if (d0 >= 0 && d0 < NA) atomicAdd(cnt + d0, 1.0f);
      if (d1 >= 0 && d1 < NA) atomicAdd(cnt + d1, 1.0f);
    }
  }
}

// ---- repack weights [K][128] -> MFMA B-fragment-major bf16 ----
__global__ __launch_bounds__(64) void repack_w(
    const void* __restrict__ w, unsigned short* __restrict__ dst,
    const int* __restrict__ fl)
{
  int wbf = fl[1];
  int f = blockIdx.x; int kt = f >> 3; int nb = f & 7; int l = threadIdx.x;
  alignas(16) unsigned short t[8];
  #pragma unroll
  for (int i = 0; i < 8; i++) {
    size_t off = (size_t)(kt * 32 + ((l >> 4) << 3) + i) * 128 + nb * 16 + (l & 15);
    t[i] = f2bf(ldv(w, off, wbf));
  }
  *(uint4*)(dst + (size_t)f * 512 + l * 8) = *(const uint4*)t;
}

// ---- one layer on a 32-row tile; 8 waves, wave w owns col-block w ----
// Two 16-row strips per wave (independent MFMA chains).
template<int KT, bool FINAL>
__device__ __forceinline__ void run_layer32w(
    const char* inbuf, int rowbIn,
    const unsigned short* __restrict__ wpL, const void* __restrict__ biasL, int wbf,
    char* outbuf,
    float* __restrict__ outSec, unsigned short* __restrict__ outBf,
    float* __restrict__ gs, float* __restrict__ gc,
    const int* __restrict__ idxS, int istr, int row0, int rowHi,
    int lane, int wave)
{
  const int colA = lane & 15;
  const int swz = (lane & 7) << 4;
  const int kb = (lane >> 4) << 4;
  float bb = ldv(biasL, wave * 16 + colA, wbf);
  f32x4 acc0 = {bb, bb, bb, bb};
  f32x4 acc1 = {bb, bb, bb, bb};
  #pragma unroll
  for (int kt = 0; kt < KT; ++kt) {
    bf16x8 b  = *(const bf16x8*)(wpL + ((size_t)(kt * 8 + wave) << 9) + lane * 8);
    bf16x8 a0 = *(const bf16x8*)(inbuf + colA * rowbIn + ((kt * 64 + kb) ^ swz));
    bf16x8 a1 = *(const bf16x8*)(inbuf + (16 + colA) * rowbIn + ((kt * 64 + kb) ^ swz));
    acc0 = __builtin_amdgcn_mfma_f32_16x16x32_bf16(a0, b, acc0, 0, 0, 0);
    acc1 = __builtin_amdgcn_mfma_f32_16x16x32_bf16(a1, b, acc1, 0, 0, 0);
  }
  const int col = wave * 16 + colA;
  #pragma unroll
  for (int s = 0; s < 2; s++) {
    f32x4 acc = s ? acc1 : acc0;
    #pragma unroll
    for (int rr = 0; rr < 4; rr++) {
      int row = s * 16 + ((lane >> 4) << 2) + rr;
      float v = acc[rr];
      if (!FINAL) {
        v = softplus_f(v);
        *(unsigned short*)(outbuf + row * 256 + ((col * 2) ^ ((row & 7) << 4))) = f2bf(v);
      } else {
        int grow = row0 + row;
        if (grow < rowHi) {
          outSec[(size_t)grow * 128 + col] = v;
          if (outBf) outBf[(size_t)grow * 128 + col] = f2bf(v);
          if (gs) {
            int g = idxS[(size_t)grow * istr];
            if (g >= 0 && g < NG) {
              atomicAdd(gs + (size_t)g * 128 + col, v);
              if (wave == 0 && colA == 0) atomicAdd(gc + g, 1.0f);
            }
          }
        }
      }
    }
  }
}

// ---- fused 3-layer MFMA MLP over 32-row tiles, 512 threads ----
// MODE 0: atom  cat=[atom | mean(pk s1,c1) | glob[amol]]     KIN=384
// MODE 1: bond  cat=[bond | A[ba0] | A[ba1] | glob]          KIN=512
// MODE 2: glob  cat=[glob | mean(f32 s1,c1) | mean(f32 s2,c2)] KIN=384
template<int KIN, int MODE>
__global__ __launch_bounds__(512, 8) void mfma_mlp(
    const void* __restrict__ x0,
    const void* __restrict__ s1, const float* __restrict__ c1,
    const float* __restrict__ s2, const float* __restrict__ c2,
    const void* __restrict__ gfv,
    const int* __restrict__ idxA, const int* __restrict__ idxS,
    const float* __restrict__ gatherA, const unsigned short* __restrict__ gatherBf,
    const unsigned short* __restrict__ wp0, const unsigned short* __restrict__ wp1,
    const unsigned short* __restrict__ wp2,
    const void* __restrict__ b0, const void* __restrict__ b1,
    const void* __restrict__ b2,
    float* __restrict__ outSec, unsigned short* __restrict__ outBf,
    float* __restrict__ gs, float* __restrict__ gc,
    int rowHi, const int* __restrict__ fl)
{
  constexpr int ROWB = KIN * 2;
  constexpr int CATB = 32 * ROWB;
  constexpr int CPR  = KIN / 8;
  __shared__ char sm[CATB + 8192];
  char* act0 = sm + CATB;   // 32 x 256B
  char* act1 = sm;          // aliases cat (dead after layer 0)
  const int tid = threadIdx.x;
  const int row0 = blockIdx.x * 32;
  const int featbf = fl[0], wbf = fl[1], istr = 1 + fl[2];

  // ---- stage concatenated input tile as swizzled bf16 ----
  for (int ch = tid; ch < 32 * CPR; ch += 512) {
    int r = ch / CPR, c8 = ch % CPR;
    int row = row0 + r;
    int seg = c8 * 8;
    uint4 h4;
    if (row >= rowHi) {
      h4 = uint4{0, 0, 0, 0};
    } else if constexpr (MODE == 0) {
      if (seg < 128)       h4 = load8bf(x0, (size_t)row * 128 + seg, featbf);
      else if (seg < 256)  h4 = mean8pk(s1, (size_t)row * 64 + ((seg - 128) >> 1), c1[row]);
      else { int g = clampi(idxA[(size_t)row * istr], NG - 1);
             h4 = load8bf(gfv, (size_t)g * 128 + seg - 256, featbf); }
    } else if constexpr (MODE == 1) {
      if (seg < 128)       h4 = load8bf(x0, (size_t)row * 128 + seg, featbf);
      else if (seg < 384) {
        int q = (seg < 256) ? 0 : 1;
        int a = clampi(idxA[(size_t)(row * 2 + q) * istr], NA - 1);
        int sc = seg - 128 - q * 128;
        if (gatherBf) h4 = *(const uint4*)(gatherBf + (size_t)a * 128 + sc);
        else          h4 = load8bf(gatherA, (size_t)a * 128 + sc, 0);
      } else { int g = clampi(idxS[(size_t)row * istr], NG - 1);
             h4 = load8bf(gfv, (size_t)g * 128 + seg - 384, featbf); }
    } else {
      if (seg < 128)       h4 = load8bf(x0, (size_t)row * 128 + seg, featbf);
      else if (seg < 256)  h4 = mean8((const float*)s1 + (size_t)row * 128 + seg - 128, c1[row]);
      else                 h4 = mean8(s2 + (size_t)row * 128 + seg - 256, c2[row]);
    }
    *(uint4*)(sm + r * ROWB + ((c8 * 16) ^ ((r & 7) << 4))) = h4;
  }
  __syncthreads();

  const int lane = tid & 63, wave = tid >> 6;
  run_layer32w<KIN / 32, false>(sm, ROWB, wp0, b0, wbf, act0,
                                nullptr, nullptr, nullptr, nullptr, nullptr, 1, 0, 0, lane, wave);
  __syncthreads();
  run_layer32w<4, false>(act0, 256, wp1, b1, wbf, act1,
                         nullptr, nullptr, nullptr, nullptr, nullptr, 1, 0, 0, lane, wave);
  __syncthreads();
  run_layer32w<4, true>(act1, 256, wp2, b2, wbf, nullptr,
                        outSec, outBf, gs, gc, idxS, istr, row0, rowHi, lane, wave);
}

extern "C" void kernel_launch(void* const* d_in, const int* in_sizes, int n_in,
                              void* d_out, int out_size, void* d_ws, size_t ws_size,
                              hipStream_t stream)
{
  const void* atomF = d_in[0];
  const void* bondF = d_in[1];
  const void* globF = d_in[2];
  const int* bondAtom = (const int*)d_in[3];
  const int* atomMol  = (const int*)d_in[4];
  const int* bondMol  = (const int*)d_in[5];
  const void* W[18];
  for (int i = 0; i < 18; i++) W[i] = d_in[6 + i];

  float* outAtom = (float*)d_out;              // f32 (proven R6/R7)
  float* outBond = outAtom + (size_t)NA * 128;
  float* outGlob = outBond + (size_t)NB * 128;

  // d_out-borrowed scratch: pk edge sums in outBond, cnt in outGlob
  unsigned int* sums = (unsigned int*)outBond;
  float* cnt = outGlob;

  // ---- contract validation ----
  const int expect[24] = {
    NA*128, NB*128, NG*128, NB*2, NA, NB,
    384*128, 128, 128*128, 128, 128*128, 128,
    512*128, 128, 128*128, 128, 128*128, 128,
    384*128, 128, 128*128, 128, 128*128, 128 };
  if (n_in != 24) { sentinel<<<1,1,0,stream>>>(outAtom, 8192.0f); return; }
  for (int i = 0; i < 24; i++)
    if (in_sizes[i] != expect[i]) {
      sentinel<<<1,1,0,stream>>>(outAtom, 16384.0f + 256.0f * (float)i);
      return;
    }
  if (out_size != (NA + NB + NG) * 128) {
    sentinel<<<1,1,0,stream>>>(outAtom, 1024.0f); return;
  }

  // ---- ws layout: fl | wp 512KB | gs f32 10.32MB | [opt] atomBf 51.2MB ----
  char* ws = (char*)d_ws;
  int* fl = (int*)ws;                                   // 256 B
  unsigned short* wp = (unsigned short*)(ws + 256);     // 512 KiB
  const size_t gsOff = 256 + 524288;
  float* gsA = (float*)(ws + gsOff);                    // NG*128 f32
  float* gcA = (float*)(ws + gsOff + 5120000);
  float* gsB = (float*)(ws + gsOff + 5160000);
  float* gcB = (float*)(ws + gsOff + 10280000);
  const size_t bfOff = gsOff + 10320000;
  unsigned short* atomBf =
      (ws_size >= bfOff + (size_t)NA * 256 + 4096) ? (unsigned short*)(ws + bfOff) : nullptr;

  probe_all<<<1, 64, 0, stream>>>((const unsigned short*)atomF,
                                  (const unsigned short*)W[0], atomMol, fl);
  hipMemsetAsync(ws + gsOff, 0, 10320000, stream);
  hipMemsetAsync(outBond, 0, (size_t)NA * 256, stream);   // pk edge sums
  hipMemsetAsync(outGlob, 0, (size_t)NA * 4, stream);     // cnt

  // ---- weight repack (fragment-major bf16); offsets in ushorts ----
  repack_w<<<96, 64, 0, stream>>>(W[0],  wp + 0,      fl);
  repack_w<<<32, 64, 0, stream>>>(W[2],  wp + 49152,  fl);
  repack_w<<<32, 64, 0, stream>>>(W[4],  wp + 65536,  fl);
  repack_w<<<128,64, 0, stream>>>(W[6],  wp + 81920,  fl);
  repack_w<<<32, 64, 0, stream>>>(W[8],  wp + 147456, fl);
  repack_w<<<32, 64, 0, stream>>>(W[10], wp + 163840, fl);
  repack_w<<<96, 64, 0, stream>>>(W[12], wp + 180224, fl);
  repack_w<<<32, 64, 0, stream>>>(W[14], wp + 229376, fl);
  repack_w<<<32, 64, 0, stream>>>(W[16], wp + 245760, fl);

  // ---- stage 0: edge-mean accumulation (packed bf16 atomics) ----
  edge_sum_pk<<<2048, 256, 0, stream>>>(bondF, bondAtom, sums, cnt, fl);

  // ---- stage 1: atoms ----
  mfma_mlp<384, 0><<<(NA + 31) / 32, 512, 0, stream>>>(
      atomF, sums, cnt, nullptr, nullptr, globF, atomMol, atomMol, nullptr, nullptr,
      wp + 0, wp + 49152, wp + 65536, W[1], W[3], W[5],
      outAtom, atomBf, gsA, gcA, NA, fl);

  // ---- stage 2: bonds ----
  mfma_mlp<512, 1><<<(NB + 31) / 32, 512, 0, stream>>>(
      bondF, nullptr, nullptr, nullptr, nullptr, globF, bondAtom, bondMol,
      outAtom, atomBf,
      wp + 81920, wp + 147456, wp + 163840, W[7], W[9], W[11],
      outBond, nullptr, gsB, gcB, NB, fl);

  // ---- stage 3: globals ----
  mfma_mlp<384, 2><<<(NG + 31) / 32, 512, 0, stream>>>(
      globF, gsA, gcA, gsB, gcB, nullptr, nullptr, nullptr, nullptr, nullptr,
      wp + 180224, wp + 229376, wp + 245760, W[13], W[15], W[17],
      outGlob, nullptr, nullptr, nullptr, NG, fl);
}